// Round 5
// baseline (304.243 us; speedup 1.0000x reference)
//
#include <hip/hip_runtime.h>

typedef __bf16 bf16x8 __attribute__((ext_vector_type(8)));
typedef float f32x4 __attribute__((ext_vector_type(4)));

#define T_LEN 200
#define NB 4096

__device__ __forceinline__ f32x4 mfma16(bf16x8 a, bf16x8 b, f32x4 c) {
    return __builtin_amdgcn_mfma_f32_16x16x32_bf16(a, b, c, 0, 0, 0);
}
// raw v_rcp_f32 (1 ulp) transcendentals; saturation exact (rcp(inf)=0)
__device__ __forceinline__ float sigf(float x) {
    return __builtin_amdgcn_rcpf(1.0f + __expf(-x));
}
__device__ __forceinline__ float tanh_fast(float x) {
    return 1.0f - 2.0f * __builtin_amdgcn_rcpf(__expf(2.0f * x) + 1.0f);
}
__device__ __forceinline__ unsigned packRNE2(float a, float b) {
    unsigned ha = (unsigned)__builtin_bit_cast(unsigned short, (__bf16)a);
    unsigned hb = (unsigned)__builtin_bit_cast(unsigned short, (__bf16)b);
    return ha | (hb << 16);
}
__device__ __forceinline__ void publish_hi(unsigned short* hp, float v) {
    __bf16 h = (__bf16)v;
    *hp = __builtin_bit_cast(unsigned short, h);
}
struct Frag { bf16x8 hi, lo; };
__device__ __forceinline__ Frag make_frag(f32x4 a, f32x4 b) {
    Frag f;
    #pragma unroll
    for (int j = 0; j < 4; j++) {
        float v = a[j]; __bf16 h = (__bf16)v;
        f.hi[j] = h; f.lo[j] = (__bf16)(v - (float)h);
    }
    #pragma unroll
    for (int j = 0; j < 4; j++) {
        float v = b[j]; __bf16 h = (__bf16)v;
        f.hi[4 + j] = h; f.lo[4 + j] = (__bf16)(v - (float)h);
    }
    return f;
}
__device__ __forceinline__ bf16x8 load_w(const float* p) {   // W: bf16 RNE hi only
    f32x4 a = *(const f32x4*)p, b = *(const f32x4*)(p + 4);
    bf16x8 w;
    #pragma unroll
    for (int j = 0; j < 4; j++) { w[j] = (__bf16)a[j]; w[4 + j] = (__bf16)b[j]; }
    return w;
}

// Wave-specialized schedule: 12 waves = 3/SIMD.
//   waves 0-3  G : GRU recurrence (h-part MFMAs + gates + score)
//   waves 4-7  A : AUGRU recurrence (pipelined 1 step behind G)
//   waves 8-11 X : x-projection producer, runs 1 step AHEAD. Computes
//                  PG(t+1)=W_ih·x + b (3 gates) and PA(t+1)=W_*x·x + b (3 gates)
//                  as f32 partials; owns x staging + global prefetch.
// Partials layout [gate][dim(64)][row(16)+4pad] f32 -> lane (c,q) reads/writes
// f32x4 at [dglob][q*4] (one b128, quad spread (5c+q)%8, ~2-way).
// Hazards (b_mid/b_end per step; all edges cross >=1 barrier):
//   sPG[2]: W by X in S0(t) buf (t+1)&1; R by G in S0(t+1) [2 barriers].
//           WAR: G read buf b at S0(t) -> X next write of b at S0(t+1) [2 barriers].
//   sPA[2]: W by X in S1(t) buf (t+1)&1; R by A in S0(t+1) [1 barrier]. WAR ok.
//   sX    : X-private. R by X in S0(t) [x(t+1)]; W by X in S1(t) [x(t+2)] (b_mid
//           between); next R at S0(t+1) (b_end between).
//   sHG   : W by G in S0(t), R by G in S1(t) [b_mid].
//   sScore[2]: W by G(wg0) in S1(t) buf t&1, R by A in S0(t+1) [b_end].
//   sHA   : W by A in S0(t), R by A in S1(t) [b_mid].
//   sRH   : W by A in S1(t), R by A in S0(t+1)/epilogue [b_end].
__global__ __launch_bounds__(768, 3)
void dien_fused(const int* __restrict__ u_idx, const int* __restrict__ i_idx,
                const int* __restrict__ seq, const float* __restrict__ item_emb,
                const float* __restrict__ user_bias, const float* __restrict__ item_bias,
                const float* __restrict__ gw_ih, const float* __restrict__ gb_ih,
                const float* __restrict__ gw_hh, const float* __restrict__ gb_hh,
                const float* __restrict__ attn_w, const float* __restrict__ attn_b,
                const float* __restrict__ wr_w, const float* __restrict__ wr_b,
                const float* __restrict__ wz_w, const float* __restrict__ wz_b,
                const float* __restrict__ wh_w, const float* __restrict__ wh_b,
                const float* __restrict__ aux_w, const float* __restrict__ aux_b,
                float* __restrict__ out)
{
    __shared__ int sSeq[16][T_LEN];
    __shared__ __align__(16) float sTP[16][64];
    __shared__ __align__(16) unsigned short sHGhi[16][72];
    __shared__ __align__(16) unsigned short sHAhi[16][72];
    __shared__ __align__(16) unsigned short sRHhi[16][72];
    __shared__ __align__(16) unsigned short sXhi[16][72];
    __shared__ __align__(16) float sPG[2][3][64][20];
    __shared__ __align__(16) float sPA[2][3][64][20];
    __shared__ float sScore[2][16];
    __shared__ float sParts[16][4];

    const int tid  = threadIdx.x;
    const int wave = tid >> 6;           // 0..11
    const int lane = tid & 63;
    const int c    = lane & 15;
    const int q    = lane >> 4;
    const int role = wave >> 2;          // 0=G, 1=A, 2=X
    const int wg   = wave & 3;
    const int dglob = wg * 16 + c;
    const int row0 = blockIdx.x * 16;
    const int xrow = wg * 4 + q;         // X: staging row
    const int xch  = c;                  // X: 4-float chunk

    // ---- stage seq indices ----
    for (int i = tid; i < 16 * T_LEN; i += 768) {
        int b = i / T_LEN, t = i - b * T_LEN;
        sSeq[b][t] = seq[(row0 + b) * T_LEN + t];
    }

    // ---- fm1 ----
    if (tid < 16) {
        int b = row0 + tid;
        out[b] = user_bias[u_idx[b]] + item_bias[i_idx[b]];
    }

    // ---- target_proj (16x64 fp32), threads 0..255 ----
    if (tid < 256) {
        int b  = tid >> 4;
        int d0 = (tid & 15) * 4;
        const float* erow = item_emb + (long)i_idx[row0 + b] * 64;
        float e[64];
        #pragma unroll
        for (int k4 = 0; k4 < 16; k4++) {
            f32x4 v = *(const f32x4*)(erow + k4 * 4);
            #pragma unroll
            for (int j = 0; j < 4; j++) e[k4 * 4 + j] = v[j];
        }
        #pragma unroll
        for (int dd = 0; dd < 4; dd++) {
            int d = d0 + dd;
            const float* wrow = attn_w + d * 64;
            float s = attn_b[d];
            #pragma unroll
            for (int k4 = 0; k4 < 16; k4++) {
                f32x4 wv = *(const f32x4*)(wrow + k4 * 4);
                #pragma unroll
                for (int j = 0; j < 4; j++) s += e[k4 * 4 + j] * wv[j];
            }
            sTP[b][d] = s;
        }
    }

    // ---- zero sHA; X stages x(0) ----
    for (int i = tid; i < 16 * 72; i += 768) ((unsigned short*)sHAhi)[i] = 0;
    if (role == 2) {
        const float* p = item_emb + (long)seq[(row0 + xrow) * T_LEN + 0] * 64 + xch * 4;
        f32x4 v = *(const f32x4*)p;
        *(uint2*)&sXhi[xrow][xch * 4] =
            make_uint2(packRNE2(v[0], v[1]), packRNE2(v[2], v[3]));
    }
    __syncthreads();

    // ---- weights (bf16-hi RNE), role-unioned ----
    // G: W[0..1]=whh_r, W[2..3]=whh_z, W[4..5]=whh_n
    // A: W[0..1]=wrh,  W[2..3]=wzh,  W[4..5]=whh_hat
    // X: W[0..5]=wih r/z/n, W[6..7]=wrx, W[8..9]=wzx, W[10..11]=whx
    bf16x8 W[12];
    if (role == 0) {
        #pragma unroll
        for (int g = 0; g < 3; g++)
            #pragma unroll
            for (int s = 0; s < 2; s++)
                W[g * 2 + s] = load_w(gw_hh + (g * 64 + dglob) * 64 + s * 32 + q * 8);
    } else if (role == 1) {
        #pragma unroll
        for (int s = 0; s < 2; s++) {
            const int fo = dglob * 128 + 64 + s * 32 + q * 8;
            W[0 + s] = load_w(wr_w + fo);
            W[2 + s] = load_w(wz_w + fo);
            W[4 + s] = load_w(wh_w + fo);
        }
    } else {
        #pragma unroll
        for (int g = 0; g < 3; g++)
            #pragma unroll
            for (int s = 0; s < 2; s++)
                W[g * 2 + s] = load_w(gw_ih + (g * 64 + dglob) * 64 + s * 32 + q * 8);
        #pragma unroll
        for (int s = 0; s < 2; s++) {
            const int fo = dglob * 128 + s * 32 + q * 8;
            W[6 + s]  = load_w(wr_w + fo);
            W[8 + s]  = load_w(wz_w + fo);
            W[10 + s] = load_w(wh_w + fo);
        }
    }

    float bD = 0.f, auxwc = 0.f;
    float xbA = 0.f, xbB = 0.f, xbC = 0.f, xbR = 0.f, xbZ = 0.f, xbH = 0.f;
    if (role == 0) {
        bD = gb_hh[128 + dglob];
        auxwc = aux_w[dglob];
    } else if (role == 2) {
        xbA = gb_ih[dglob] + gb_hh[dglob];
        xbB = gb_ih[64 + dglob] + gb_hh[64 + dglob];
        xbC = gb_ih[128 + dglob];
        xbR = wr_b[dglob];
        xbZ = wz_b[dglob];
        xbH = wh_b[dglob];
    }

    // TP as B-fragment (G only)
    Frag tpB0, tpB1;
    if (role == 0) {
        tpB0 = make_frag(*(const f32x4*)&sTP[c][q * 8], *(const f32x4*)&sTP[c][q * 8 + 4]);
        tpB1 = make_frag(*(const f32x4*)&sTP[c][32 + q * 8], *(const f32x4*)&sTP[c][32 + q * 8 + 4]);
    }

    // ---- X prologue-step: publish P(0) into buf 0; load x(1) ----
    f32x4 xn1, xnxt;
    if (role == 2) {
        bf16x8 x0 = *(const bf16x8*)&sXhi[c][q * 8];
        bf16x8 x1 = *(const bf16x8*)&sXhi[c][32 + q * 8];
        f32x4 a0 = {xbA, xbA, xbA, xbA};
        a0 = mfma16(x0, W[0], a0); a0 = mfma16(x1, W[1], a0);
        f32x4 a1 = {xbB, xbB, xbB, xbB};
        a1 = mfma16(x0, W[2], a1); a1 = mfma16(x1, W[3], a1);
        f32x4 a2 = {xbC, xbC, xbC, xbC};
        a2 = mfma16(x0, W[4], a2); a2 = mfma16(x1, W[5], a2);
        *(f32x4*)&sPG[0][0][dglob][q * 4] = a0;
        *(f32x4*)&sPG[0][1][dglob][q * 4] = a1;
        *(f32x4*)&sPG[0][2][dglob][q * 4] = a2;
        f32x4 a3 = {xbR, xbR, xbR, xbR};
        a3 = mfma16(x0, W[6], a3); a3 = mfma16(x1, W[7], a3);
        f32x4 a4 = {xbZ, xbZ, xbZ, xbZ};
        a4 = mfma16(x0, W[8], a4); a4 = mfma16(x1, W[9], a4);
        f32x4 a5 = {xbH, xbH, xbH, xbH};
        a5 = mfma16(x0, W[10], a5); a5 = mfma16(x1, W[11], a5);
        *(f32x4*)&sPA[0][0][dglob][q * 4] = a3;
        *(f32x4*)&sPA[0][1][dglob][q * 4] = a4;
        *(f32x4*)&sPA[0][2][dglob][q * 4] = a5;
        xn1 = *(const f32x4*)(item_emb + (long)sSeq[xrow][1] * 64 + xch * 4);
    }
    __syncthreads();   // P(0) visible; X's frag-read of x(0) complete (WAR)
    if (role == 2) {
        *(uint2*)&sXhi[xrow][xch * 4] =
            make_uint2(packRNE2(xn1[0], xn1[1]), packRNE2(xn1[2], xn1[3]));
        xnxt = *(const f32x4*)(item_emb + (long)sSeq[xrow][2] * 64 + xch * 4);
    }
    __syncthreads();   // x(1) staged

    // ---- state ----
    float hst[4] = {0.f, 0.f, 0.f, 0.f};   // G: hg(t); A: ha(t-1)
    bf16x8 fr0, fr1;                        // G: hg(t-1) frags; X: x frags carry
    #pragma unroll
    for (int j = 0; j < 8; j++) { fr0[j] = (__bf16)0.f; fr1[j] = (__bf16)0.f; }
    f32x4 aAH = {0.f, 0.f, 0.f, 0.f};
    float z_c[4] = {0.f, 0.f, 0.f, 0.f};
    f32x4 aAR, aAZ;
    f32x4 xg;

    for (int t = 0; t < T_LEN; t++) {
        const int cur = t & 1, nxt = (t + 1) & 1;

        // ================= phase 0 =================
        if (role == 0) {
            f32x4 pR = *(const f32x4*)&sPG[cur][0][dglob][q * 4];
            f32x4 pZ = *(const f32x4*)&sPG[cur][1][dglob][q * 4];
            f32x4 pN = *(const f32x4*)&sPG[cur][2][dglob][q * 4];
            f32x4 z4 = {0.f, 0.f, 0.f, 0.f};
            f32x4 accR = mfma16(fr0, W[0], z4);  accR = mfma16(fr1, W[1], accR);
            f32x4 accZ = mfma16(fr0, W[2], z4);  accZ = mfma16(fr1, W[3], accZ);
            f32x4 accNH = {bD, bD, bD, bD};
            accNH = mfma16(fr0, W[4], accNH); accNH = mfma16(fr1, W[5], accNH);
            accR += pR; accZ += pZ;
            #pragma unroll
            for (int i = 0; i < 4; i++) {
                float r = sigf(accR[i]);
                float z = sigf(accZ[i]);
                float n = tanh_fast(pN[i] + r * accNH[i]);
                float hn = n + z * (hst[i] - n);
                hst[i] = hn;
                publish_hi(&sHGhi[q * 4 + i][dglob], hn);
            }
        } else if (role == 1) {
            if (t > 0) {
                bf16x8 rh0 = *(const bf16x8*)&sRHhi[c][q * 8];
                bf16x8 rh1 = *(const bf16x8*)&sRHhi[c][32 + q * 8];
                aAH = mfma16(rh0, W[4], aAH); aAH = mfma16(rh1, W[5], aAH);
                #pragma unroll
                for (int i = 0; i < 4; i++) {
                    int rr = q * 4 + i;
                    float a = sScore[(t - 1) & 1][rr];   // pre-sigmoided
                    float hh = tanh_fast(aAH[i]);
                    float zz = a * z_c[i];
                    float hv = hst[i] + zz * (hh - hst[i]);
                    hst[i] = hv;
                    publish_hi(&sHAhi[rr][dglob], hv);
                }
            }
            aAR = *(const f32x4*)&sPA[cur][0][dglob][q * 4];
            aAZ = *(const f32x4*)&sPA[cur][1][dglob][q * 4];
            aAH = *(const f32x4*)&sPA[cur][2][dglob][q * 4];
        } else {
            // X: frag-read x(t+1); compute PG(t+1); prefetch x(t+3)
            fr0 = *(const bf16x8*)&sXhi[c][q * 8];
            fr1 = *(const bf16x8*)&sXhi[c][32 + q * 8];
            int tn = t + 3; if (tn > T_LEN - 1) tn = T_LEN - 1;
            xg = *(const f32x4*)(item_emb + (long)sSeq[xrow][tn] * 64 + xch * 4);
            f32x4 a0 = {xbA, xbA, xbA, xbA};
            a0 = mfma16(fr0, W[0], a0); a0 = mfma16(fr1, W[1], a0);
            f32x4 a1 = {xbB, xbB, xbB, xbB};
            a1 = mfma16(fr0, W[2], a1); a1 = mfma16(fr1, W[3], a1);
            f32x4 a2 = {xbC, xbC, xbC, xbC};
            a2 = mfma16(fr0, W[4], a2); a2 = mfma16(fr1, W[5], a2);
            *(f32x4*)&sPG[nxt][0][dglob][q * 4] = a0;
            *(f32x4*)&sPG[nxt][1][dglob][q * 4] = a1;
            *(f32x4*)&sPG[nxt][2][dglob][q * 4] = a2;
        }

        __syncthreads();  // b_mid

        // ================= phase 1 =================
        if (role == 0) {
            fr0 = *(const bf16x8*)&sHGhi[c][q * 8];
            fr1 = *(const bf16x8*)&sHGhi[c][32 + q * 8];
            f32x4 sc = {0.f, 0.f, 0.f, 0.f};
            sc = mfma16(fr0, tpB0.hi, sc); sc = mfma16(fr0, tpB0.lo, sc);
            sc = mfma16(fr1, tpB1.hi, sc); sc = mfma16(fr1, tpB1.lo, sc);
            if (wg == 0 && (c >> 2) == q) {
                int i = c & 3;
                float d = (i == 0) ? sc[0] : (i == 1) ? sc[1] : (i == 2) ? sc[2] : sc[3];
                sScore[cur][c] = sigf(d);
            }
        } else if (role == 1) {
            bf16x8 ha0 = *(const bf16x8*)&sHAhi[c][q * 8];
            bf16x8 ha1 = *(const bf16x8*)&sHAhi[c][32 + q * 8];
            aAR = mfma16(ha0, W[0], aAR); aAR = mfma16(ha1, W[1], aAR);
            aAZ = mfma16(ha0, W[2], aAZ); aAZ = mfma16(ha1, W[3], aAZ);
            #pragma unroll
            for (int i = 0; i < 4; i++) {
                float r = sigf(aAR[i]);
                z_c[i]  = sigf(aAZ[i]);
                float rh = r * hst[i];
                publish_hi(&sRHhi[q * 4 + i][dglob], rh);
            }
        } else {
            // X: compute PA(t+1) from x(t+1) frags (regs); stage x(t+2)
            f32x4 a3 = {xbR, xbR, xbR, xbR};
            a3 = mfma16(fr0, W[6], a3); a3 = mfma16(fr1, W[7], a3);
            f32x4 a4 = {xbZ, xbZ, xbZ, xbZ};
            a4 = mfma16(fr0, W[8], a4); a4 = mfma16(fr1, W[9], a4);
            f32x4 a5 = {xbH, xbH, xbH, xbH};
            a5 = mfma16(fr0, W[10], a5); a5 = mfma16(fr1, W[11], a5);
            *(f32x4*)&sPA[nxt][0][dglob][q * 4] = a3;
            *(f32x4*)&sPA[nxt][1][dglob][q * 4] = a4;
            *(f32x4*)&sPA[nxt][2][dglob][q * 4] = a5;
            *(uint2*)&sXhi[xrow][xch * 4] =
                make_uint2(packRNE2(xnxt[0], xnxt[1]), packRNE2(xnxt[2], xnxt[3]));
            xnxt = xg;
        }

        __syncthreads();  // b_end
    }

    // ---- epilogue: A finalizes ha(T-1), writes attn_vec ----
    if (role == 1) {
        bf16x8 rh0 = *(const bf16x8*)&sRHhi[c][q * 8];
        bf16x8 rh1 = *(const bf16x8*)&sRHhi[c][32 + q * 8];
        aAH = mfma16(rh0, W[4], aAH); aAH = mfma16(rh1, W[5], aAH);
        #pragma unroll
        for (int i = 0; i < 4; i++) {
            int rr = q * 4 + i;
            float a = sScore[(T_LEN - 1) & 1][rr];
            float hh = tanh_fast(aAH[i]);
            float zz = a * z_c[i];
            float hv = hst[i] + zz * (hh - hst[i]);
            out[NB + (row0 + rr) * 64 + dglob] = hv;
        }
    }

    // ---- aux_logits from hg(T-1) (G group) ----
    if (role == 0) {
        float pa[4];
        #pragma unroll
        for (int i = 0; i < 4; i++) pa[i] = hst[i] * auxwc;
        #pragma unroll
        for (int m = 1; m < 16; m <<= 1) {
            #pragma unroll
            for (int i = 0; i < 4; i++) pa[i] += __shfl_xor(pa[i], m, 64);
        }
        if (c == 0) {
            #pragma unroll
            for (int i = 0; i < 4; i++) sParts[q * 4 + i][wg] = pa[i];
        }
    }
    __syncthreads();
    if (tid < 16) {
        out[NB + NB * 64 + row0 + tid] =
            sParts[tid][0] + sParts[tid][1] + sParts[tid][2] + sParts[tid][3] + aux_b[0];
    }
}

extern "C" void kernel_launch(void* const* d_in, const int* in_sizes, int n_in,
                              void* d_out, int out_size, void* d_ws, size_t ws_size,
                              hipStream_t stream) {
    dien_fused<<<dim3(256), dim3(768), 0, stream>>>(
        (const int*)d_in[0],      // u_idx
        (const int*)d_in[1],      // i_idx
        (const int*)d_in[2],      // seq
        (const float*)d_in[3],    // item_emb
        (const float*)d_in[4],    // user_bias
        (const float*)d_in[5],    // item_bias
        (const float*)d_in[6],    // gru_w_ih
        (const float*)d_in[7],    // gru_b_ih
        (const float*)d_in[8],    // gru_w_hh
        (const float*)d_in[9],    // gru_b_hh
        (const float*)d_in[10],   // attn_w
        (const float*)d_in[11],   // attn_b
        (const float*)d_in[12],   // wr_w
        (const float*)d_in[13],   // wr_b
        (const float*)d_in[14],   // wz_w
        (const float*)d_in[15],   // wz_b
        (const float*)d_in[16],   // wh_w
        (const float*)d_in[17],   // wh_b
        (const float*)d_in[18],   // aux_w
        (const float*)d_in[19],   // aux_b
        (float*)d_out);
}